// Round 5
// baseline (596.925 us; speedup 1.0000x reference)
//
#include <hip/hip_runtime.h>

// Causal flash attention fwd: B=4,H=16,S=2048,D=64. fp32 I/O, bf16 MFMA compute.
// R5: operand-swapped matmuls (S^T = K·Q^T, O^T = V^T·P^T) so the P tile is
// written as contiguous b64 and read as b128 B-fragments (P round-trip 40->12
// LDS insts). XOR-swizzled unpadded LDS (40960 B exact -> 4 blocks/CU), b128
// fragment loads, scalar per-lane softmax denom, LDS-transpose epilogue.
// Layouts (HW-verified, learn_hip m89/m91): A[m=lane&15][k=quad*8+j],
// B[k=quad*8+j][n=lane&15], C/D: col=lane&15, row=quad*4+reg.

typedef short bf16x8 __attribute__((ext_vector_type(8)));
typedef float f32x4  __attribute__((ext_vector_type(4)));

#define S_LEN 2048
#define D_DIM 64
#define BM 64
#define BN 64
#define SC_LOG2E 0.18033688011112042f   // (1/8) * log2(e)

// pack two fp32 -> bf16x2 dword by truncation (1 v_perm_b32)
__device__ __forceinline__ unsigned pk2(float lo, float hi) {
    return __builtin_amdgcn_perm(__builtin_bit_cast(unsigned, hi),
                                 __builtin_bit_cast(unsigned, lo), 0x07060302u);
}

__global__ __launch_bounds__(256, 4) void fattn_kernel(
    const float* __restrict__ Q, const float* __restrict__ K,
    const float* __restrict__ V, float* __restrict__ O)
{
    // all tiles xor-swizzled on 16B chunks: chunk' = chunk ^ (row & 7) -- no pads
    __shared__ short Kl[2][BN * D_DIM];   // [kv][d]   16384 B
    __shared__ short Vt[2][D_DIM * BN];   // [d][kv]   16384 B
    __shared__ short Pw[4][16 * BN];      // per-wave P[q][kv]  8192 B

    const int t    = threadIdx.x;
    const int wid  = t >> 6;
    const int lane = t & 63;
    const int quad = lane >> 4;
    const int lcol = lane & 15;
    const int l7   = lcol & 7;

    const int na  = blockIdx.x + 1;           // 1..16 (short q-tile)
    const int nb  = 32 - blockIdx.x;          // 32..17 (long q-tile)
    const int q0a = blockIdx.x * BM;
    const int q0b = (31 - blockIdx.x) * BM;

    const int bh = blockIdx.y;
    const size_t base = (size_t)bh * (S_LEN * D_DIM);
    const float* Qh = Q + base;
    const float* Kh = K + base;
    const float* Vh = V + base;
    float*       Oh = O + base;

    // staging coords
    const int skv = t >> 2;                       // K row
    const int sc0 = (t & 3) * 2;                  // K 16B-chunk pair base
    const int kw0 = skv * 64 + ((sc0 ^ (skv & 7)) * 8);
    const int kw1 = skv * 64 + (((sc0 + 1) ^ (skv & 7)) * 8);
    const int vd  = (t >> 5) * 8;                 // V col block (d)
    const int dc  = t & 31;                       // V dword col (kv pair)
    const int vkv = dc * 2;

    // loop-invariant fragment-read chunk terms (shorts)
    const int fko0 = ((quad    ) ^ l7) * 8;       // k-half 0
    const int fko1 = ((quad + 4) ^ l7) * 8;       // k-half 1
    const int prow = lcol * 64;                   // P row base (shorts)

    // ---- Q fragments (serve as B-operand of S^T = K·Q^T) ----
    bf16x8 aqA0, aqA1, aqB0, aqB1;
    {
        const float* qp = Qh + (size_t)(q0a + wid * 16 + lcol) * D_DIM;
        float4 a = *(const float4*)(qp + quad * 8);
        float4 b = *(const float4*)(qp + quad * 8 + 4);
        float4 c = *(const float4*)(qp + 32 + quad * 8);
        float4 d = *(const float4*)(qp + 32 + quad * 8 + 4);
        union { unsigned u[4]; bf16x8 v; } r0, r1;
        r0.u[0] = pk2(a.x, a.y); r0.u[1] = pk2(a.z, a.w);
        r0.u[2] = pk2(b.x, b.y); r0.u[3] = pk2(b.z, b.w);
        r1.u[0] = pk2(c.x, c.y); r1.u[1] = pk2(c.z, c.w);
        r1.u[2] = pk2(d.x, d.y); r1.u[3] = pk2(d.z, d.w);
        aqA0 = r0.v; aqA1 = r1.v;
    }
    {
        const float* qp = Qh + (size_t)(q0b + wid * 16 + lcol) * D_DIM;
        float4 a = *(const float4*)(qp + quad * 8);
        float4 b = *(const float4*)(qp + quad * 8 + 4);
        float4 c = *(const float4*)(qp + 32 + quad * 8);
        float4 d = *(const float4*)(qp + 32 + quad * 8 + 4);
        union { unsigned u[4]; bf16x8 v; } r0, r1;
        r0.u[0] = pk2(a.x, a.y); r0.u[1] = pk2(a.z, a.w);
        r0.u[2] = pk2(b.x, b.y); r0.u[3] = pk2(b.z, b.w);
        r1.u[0] = pk2(c.x, c.y); r1.u[1] = pk2(c.z, c.w);
        r1.u[2] = pk2(d.x, d.y); r1.u[3] = pk2(d.z, d.w);
        aqB0 = r0.v; aqB1 = r1.v;
    }

    f32x4 oA[4], oB[4];                 // O^T accum: row=d=quad*4+r, col=q=lcol
    #pragma unroll
    for (int nt = 0; nt < 4; ++nt) {
        oA[nt] = f32x4{0.f, 0.f, 0.f, 0.f};
        oB[nt] = f32x4{0.f, 0.f, 0.f, 0.f};
    }
    float lpA = 0.f, lpB = 0.f;         // softmax denom for q = lcol (quad-partial)
    const int row_q = wid * 16 + lcol;

    float4 kr0, kr1, kr2, kr3, vr0, vr1, vr2, vr3;
#define PREFETCH(tl) do {                                                     \
        const float* kp = Kh + (size_t)((tl) * BN + skv) * D_DIM + sc0 * 8;   \
        kr0 = *(const float4*)(kp);     kr1 = *(const float4*)(kp + 4);       \
        kr2 = *(const float4*)(kp + 8); kr3 = *(const float4*)(kp + 12);      \
        const float* vp = Vh + (size_t)((tl) * BN + vkv) * D_DIM + vd;        \
        vr0 = *(const float4*)(vp);         vr1 = *(const float4*)(vp + 4);   \
        vr2 = *(const float4*)(vp + D_DIM); vr3 = *(const float4*)(vp + D_DIM + 4); \
    } while (0)

#define STAGE(buf) do {                                                       \
        short* kb = Kl[buf];                                                  \
        *(uint4*)(kb + kw0) = make_uint4(pk2(kr0.x, kr0.y), pk2(kr0.z, kr0.w),\
                                         pk2(kr1.x, kr1.y), pk2(kr1.z, kr1.w));\
        *(uint4*)(kb + kw1) = make_uint4(pk2(kr2.x, kr2.y), pk2(kr2.z, kr2.w),\
                                         pk2(kr3.x, kr3.y), pk2(kr3.z, kr3.w));\
        unsigned* vb = (unsigned*)Vt[buf];                                    \
        const float a[8] = {vr0.x, vr0.y, vr0.z, vr0.w, vr1.x, vr1.y, vr1.z, vr1.w}; \
        const float b[8] = {vr2.x, vr2.y, vr2.z, vr2.w, vr3.x, vr3.y, vr3.z, vr3.w}; \
        _Pragma("unroll")                                                     \
        for (int i = 0; i < 8; ++i)                                           \
            vb[(vd + i) * 32 + (((dc >> 2) ^ i) * 4) + (dc & 3)] = pk2(a[i], b[i]); \
    } while (0)

    PREFETCH(0);
    STAGE(0);
    PREFETCH(1);
    __syncthreads();

    for (int tile = 0; tile < nb; ++tile) {
        const int cur = tile & 1;
        const short* Kb = Kl[cur];
        const short* Vb = Vt[cur];
        const bool doA = (tile < na);

        // ---- S^T = K·Q^T : A = K-frag, B = Q-frag ----
        f32x4 sA[4], sB[4];
        #pragma unroll
        for (int ct = 0; ct < 4; ++ct) {
            const int rb = (ct * 16 + lcol) * 64;
            const bf16x8 k0 = *(const bf16x8*)(Kb + rb + fko0);
            const bf16x8 k1 = *(const bf16x8*)(Kb + rb + fko1);
            f32x4 z = f32x4{0.f, 0.f, 0.f, 0.f};
            z = __builtin_amdgcn_mfma_f32_16x16x32_bf16(k0, aqB0, z, 0, 0, 0);
            z = __builtin_amdgcn_mfma_f32_16x16x32_bf16(k1, aqB1, z, 0, 0, 0);
            sB[ct] = z;
            if (doA) {
                f32x4 y = f32x4{0.f, 0.f, 0.f, 0.f};
                y = __builtin_amdgcn_mfma_f32_16x16x32_bf16(k0, aqA0, y, 0, 0, 0);
                y = __builtin_amdgcn_mfma_f32_16x16x32_bf16(k1, aqA1, y, 0, 0, 0);
                sA[ct] = y;
            }
        }

        short* pw = Pw[wid];

        // ---- softmax numerator B -> P LDS (contiguous b64 writes) ----
        {
            const bool diag = (tile == nb - 1);
            #pragma unroll
            for (int ct = 0; ct < 4; ++ct) {
                float e[4];
                #pragma unroll
                for (int r = 0; r < 4; ++r) {
                    float x = sB[ct][r] * SC_LOG2E;
                    if (diag && (ct * 16 + quad * 4 + r > row_q)) x = -__builtin_inff();
                    e[r] = __builtin_amdgcn_exp2f(x);
                    lpB += e[r];
                }
                *(uint2*)(pw + prow + (((ct * 2 + (quad >> 1)) ^ l7) * 8) + (quad & 1) * 4)
                    = make_uint2(pk2(e[0], e[1]), pk2(e[2], e[3]));
            }
        }
        const bf16x8 pB0 = *(const bf16x8*)(pw + prow + fko0);
        const bf16x8 pB1 = *(const bf16x8*)(pw + prow + fko1);

        // ---- softmax numerator A (reuses Pw; wave-private, DS in-order) ----
        bf16x8 pA0, pA1;
        if (doA) {
            const bool diag = (tile == na - 1);
            #pragma unroll
            for (int ct = 0; ct < 4; ++ct) {
                float e[4];
                #pragma unroll
                for (int r = 0; r < 4; ++r) {
                    float x = sA[ct][r] * SC_LOG2E;
                    if (diag && (ct * 16 + quad * 4 + r > row_q)) x = -__builtin_inff();
                    e[r] = __builtin_amdgcn_exp2f(x);
                    lpA += e[r];
                }
                *(uint2*)(pw + prow + (((ct * 2 + (quad >> 1)) ^ l7) * 8) + (quad & 1) * 4)
                    = make_uint2(pk2(e[0], e[1]), pk2(e[2], e[3]));
            }
            pA0 = *(const bf16x8*)(pw + prow + fko0);
            pA1 = *(const bf16x8*)(pw + prow + fko1);
        }

        // ---- O^T += V^T·P^T : A = V-frag, B = P-frag ----
        #pragma unroll
        for (int nt = 0; nt < 4; ++nt) {
            const int rb = (nt * 16 + lcol) * 64;
            const bf16x8 v0 = *(const bf16x8*)(Vb + rb + fko0);
            const bf16x8 v1 = *(const bf16x8*)(Vb + rb + fko1);
            oB[nt] = __builtin_amdgcn_mfma_f32_16x16x32_bf16(v0, pB0, oB[nt], 0, 0, 0);
            oB[nt] = __builtin_amdgcn_mfma_f32_16x16x32_bf16(v1, pB1, oB[nt], 0, 0, 0);
            if (doA) {
                oA[nt] = __builtin_amdgcn_mfma_f32_16x16x32_bf16(v0, pA0, oA[nt], 0, 0, 0);
                oA[nt] = __builtin_amdgcn_mfma_f32_16x16x32_bf16(v1, pA1, oA[nt], 0, 0, 0);
            }
        }

        // ---- stage next tile into other buffer; prefetch tile+2 ----
        if (tile + 1 < nb) {
            STAGE(cur ^ 1);
            if (tile + 2 < nb) PREFETCH(tile + 2);
        }
        __syncthreads();
    }

    // ---- reduce softmax denom across quads (q = lcol) ----
    lpA += __shfl_xor(lpA, 16, 64); lpA += __shfl_xor(lpA, 32, 64);
    lpB += __shfl_xor(lpB, 16, 64); lpB += __shfl_xor(lpB, 32, 64);
    const float invA = 1.0f / lpA;
    const float invB = 1.0f / lpB;

    // ---- epilogue: O^T -> LDS transpose (reuse K/V buffers) -> coalesced store
    float* oa = (float*)Kl + wid * 1024;   // 16 q-rows x 64 d (swizzled chunks)
    float* ob = (float*)Vt + wid * 1024;
    #pragma unroll
    for (int nt = 0; nt < 4; ++nt) {
        const int off = lcol * 64 + (((nt * 4 + quad) ^ lcol) * 4);
        *(f32x4*)(oa + off) = oA[nt] * invA;
        *(f32x4*)(ob + off) = oB[nt] * invB;
    }
    const int qr = lane >> 2;
    const int cl = lane & 3;
    float* opA = Oh + (size_t)(q0a + wid * 16 + qr) * D_DIM;
    float* opB = Oh + (size_t)(q0b + wid * 16 + qr) * D_DIM;
    #pragma unroll
    for (int c = 0; c < 4; ++c) {
        const int off = qr * 64 + (((cl * 4 + c) ^ qr) * 4);
        *(float4*)(opA + cl * 16 + c * 4) = *(const float4*)(oa + off);
        *(float4*)(opB + cl * 16 + c * 4) = *(const float4*)(ob + off);
    }
}

extern "C" void kernel_launch(void* const* d_in, const int* in_sizes, int n_in,
                              void* d_out, int out_size, void* d_ws, size_t ws_size,
                              hipStream_t stream) {
    const float* Q = (const float*)d_in[0];
    const float* K = (const float*)d_in[1];
    const float* V = (const float*)d_in[2];
    float*       O = (float*)d_out;
    dim3 grid(S_LEN / BM / 2, 4 * 16);   // 16 complementary q-pairs x 64 heads
    fattn_kernel<<<grid, 256, 0, stream>>>(Q, K, V, O);
}

// Round 6
// 280.225 us; speedup vs baseline: 2.1302x; 2.1302x over previous
//
#include <hip/hip_runtime.h>

// Causal flash attention fwd: B=4,H=16,S=2048,D=64. fp32 I/O, bf16 MFMA compute.
// R6 = R5 structure with __launch_bounds__(256,3) restored. R5's (256,4) cut the
// reg cap to 128 < ~148 live regs -> scratch spills (WRITE_SIZE 33->730 MB, 3.6x
// slower). 3 waves/EU cap (~170 regs) fits with zero spill (proven in R4).
// Operand-swapped matmuls (S^T = K·Q^T, O^T = V^T·P^T): P written as contiguous
// b64, read as b128 B-fragments. XOR-swizzled unpadded LDS, b128 fragment loads,
// per-lane scalar softmax denom, LDS-transpose coalesced epilogue.
// Layouts (HW-verified, learn_hip m89/m91): A[m=lane&15][k=quad*8+j],
// B[k=quad*8+j][n=lane&15], C/D: col=lane&15, row=quad*4+reg.

typedef short bf16x8 __attribute__((ext_vector_type(8)));
typedef float f32x4  __attribute__((ext_vector_type(4)));

#define S_LEN 2048
#define D_DIM 64
#define BM 64
#define BN 64
#define SC_LOG2E 0.18033688011112042f   // (1/8) * log2(e)

// pack two fp32 -> bf16x2 dword by truncation (1 v_perm_b32)
__device__ __forceinline__ unsigned pk2(float lo, float hi) {
    return __builtin_amdgcn_perm(__builtin_bit_cast(unsigned, hi),
                                 __builtin_bit_cast(unsigned, lo), 0x07060302u);
}

__global__ __launch_bounds__(256, 3) void fattn_kernel(
    const float* __restrict__ Q, const float* __restrict__ K,
    const float* __restrict__ V, float* __restrict__ O)
{
    // all tiles xor-swizzled on 16B chunks: chunk' = chunk ^ (row & 7) -- no pads
    __shared__ short Kl[2][BN * D_DIM];   // [kv][d]   16384 B
    __shared__ short Vt[2][D_DIM * BN];   // [d][kv]   16384 B
    __shared__ short Pw[4][16 * BN];      // per-wave P[q][kv]  8192 B

    const int t    = threadIdx.x;
    const int wid  = t >> 6;
    const int lane = t & 63;
    const int quad = lane >> 4;
    const int lcol = lane & 15;
    const int l7   = lcol & 7;

    const int na  = blockIdx.x + 1;           // 1..16 (short q-tile)
    const int nb  = 32 - blockIdx.x;          // 32..17 (long q-tile)
    const int q0a = blockIdx.x * BM;
    const int q0b = (31 - blockIdx.x) * BM;

    const int bh = blockIdx.y;
    const size_t base = (size_t)bh * (S_LEN * D_DIM);
    const float* Qh = Q + base;
    const float* Kh = K + base;
    const float* Vh = V + base;
    float*       Oh = O + base;

    // staging coords
    const int skv = t >> 2;                       // K row
    const int sc0 = (t & 3) * 2;                  // K 16B-chunk pair base
    const int kw0 = skv * 64 + ((sc0 ^ (skv & 7)) * 8);
    const int kw1 = skv * 64 + (((sc0 + 1) ^ (skv & 7)) * 8);
    const int vd  = (t >> 5) * 8;                 // V col block (d)
    const int dc  = t & 31;                       // V dword col (kv pair)
    const int vkv = dc * 2;

    // loop-invariant fragment-read chunk terms (shorts)
    const int fko0 = ((quad    ) ^ l7) * 8;       // k-half 0
    const int fko1 = ((quad + 4) ^ l7) * 8;       // k-half 1
    const int prow = lcol * 64;                   // P row base (shorts)

    // ---- Q fragments (serve as B-operand of S^T = K·Q^T) ----
    bf16x8 aqA0, aqA1, aqB0, aqB1;
    {
        const float* qp = Qh + (size_t)(q0a + wid * 16 + lcol) * D_DIM;
        float4 a = *(const float4*)(qp + quad * 8);
        float4 b = *(const float4*)(qp + quad * 8 + 4);
        float4 c = *(const float4*)(qp + 32 + quad * 8);
        float4 d = *(const float4*)(qp + 32 + quad * 8 + 4);
        union { unsigned u[4]; bf16x8 v; } r0, r1;
        r0.u[0] = pk2(a.x, a.y); r0.u[1] = pk2(a.z, a.w);
        r0.u[2] = pk2(b.x, b.y); r0.u[3] = pk2(b.z, b.w);
        r1.u[0] = pk2(c.x, c.y); r1.u[1] = pk2(c.z, c.w);
        r1.u[2] = pk2(d.x, d.y); r1.u[3] = pk2(d.z, d.w);
        aqA0 = r0.v; aqA1 = r1.v;
    }
    {
        const float* qp = Qh + (size_t)(q0b + wid * 16 + lcol) * D_DIM;
        float4 a = *(const float4*)(qp + quad * 8);
        float4 b = *(const float4*)(qp + quad * 8 + 4);
        float4 c = *(const float4*)(qp + 32 + quad * 8);
        float4 d = *(const float4*)(qp + 32 + quad * 8 + 4);
        union { unsigned u[4]; bf16x8 v; } r0, r1;
        r0.u[0] = pk2(a.x, a.y); r0.u[1] = pk2(a.z, a.w);
        r0.u[2] = pk2(b.x, b.y); r0.u[3] = pk2(b.z, b.w);
        r1.u[0] = pk2(c.x, c.y); r1.u[1] = pk2(c.z, c.w);
        r1.u[2] = pk2(d.x, d.y); r1.u[3] = pk2(d.z, d.w);
        aqB0 = r0.v; aqB1 = r1.v;
    }

    f32x4 oA[4], oB[4];                 // O^T accum: row=d=quad*4+r, col=q=lcol
    #pragma unroll
    for (int nt = 0; nt < 4; ++nt) {
        oA[nt] = f32x4{0.f, 0.f, 0.f, 0.f};
        oB[nt] = f32x4{0.f, 0.f, 0.f, 0.f};
    }
    float lpA = 0.f, lpB = 0.f;         // softmax denom for q = lcol (quad-partial)
    const int row_q = wid * 16 + lcol;

    float4 kr0, kr1, kr2, kr3, vr0, vr1, vr2, vr3;
#define PREFETCH(tl) do {                                                     \
        const float* kp = Kh + (size_t)((tl) * BN + skv) * D_DIM + sc0 * 8;   \
        kr0 = *(const float4*)(kp);     kr1 = *(const float4*)(kp + 4);       \
        kr2 = *(const float4*)(kp + 8); kr3 = *(const float4*)(kp + 12);      \
        const float* vp = Vh + (size_t)((tl) * BN + vkv) * D_DIM + vd;        \
        vr0 = *(const float4*)(vp);         vr1 = *(const float4*)(vp + 4);   \
        vr2 = *(const float4*)(vp + D_DIM); vr3 = *(const float4*)(vp + D_DIM + 4); \
    } while (0)

#define STAGE(buf) do {                                                       \
        short* kb = Kl[buf];                                                  \
        *(uint4*)(kb + kw0) = make_uint4(pk2(kr0.x, kr0.y), pk2(kr0.z, kr0.w),\
                                         pk2(kr1.x, kr1.y), pk2(kr1.z, kr1.w));\
        *(uint4*)(kb + kw1) = make_uint4(pk2(kr2.x, kr2.y), pk2(kr2.z, kr2.w),\
                                         pk2(kr3.x, kr3.y), pk2(kr3.z, kr3.w));\
        unsigned* vb = (unsigned*)Vt[buf];                                    \
        const float a[8] = {vr0.x, vr0.y, vr0.z, vr0.w, vr1.x, vr1.y, vr1.z, vr1.w}; \
        const float b[8] = {vr2.x, vr2.y, vr2.z, vr2.w, vr3.x, vr3.y, vr3.z, vr3.w}; \
        _Pragma("unroll")                                                     \
        for (int i = 0; i < 8; ++i)                                           \
            vb[(vd + i) * 32 + (((dc >> 2) ^ i) * 4) + (dc & 3)] = pk2(a[i], b[i]); \
    } while (0)

    PREFETCH(0);
    STAGE(0);
    PREFETCH(1);
    __syncthreads();

    for (int tile = 0; tile < nb; ++tile) {
        const int cur = tile & 1;
        const short* Kb = Kl[cur];
        const short* Vb = Vt[cur];
        const bool doA = (tile < na);

        // ---- S^T = K·Q^T : A = K-frag, B = Q-frag ----
        f32x4 sA[4], sB[4];
        #pragma unroll
        for (int ct = 0; ct < 4; ++ct) {
            const int rb = (ct * 16 + lcol) * 64;
            const bf16x8 k0 = *(const bf16x8*)(Kb + rb + fko0);
            const bf16x8 k1 = *(const bf16x8*)(Kb + rb + fko1);
            f32x4 z = f32x4{0.f, 0.f, 0.f, 0.f};
            z = __builtin_amdgcn_mfma_f32_16x16x32_bf16(k0, aqB0, z, 0, 0, 0);
            z = __builtin_amdgcn_mfma_f32_16x16x32_bf16(k1, aqB1, z, 0, 0, 0);
            sB[ct] = z;
            if (doA) {
                f32x4 y = f32x4{0.f, 0.f, 0.f, 0.f};
                y = __builtin_amdgcn_mfma_f32_16x16x32_bf16(k0, aqA0, y, 0, 0, 0);
                y = __builtin_amdgcn_mfma_f32_16x16x32_bf16(k1, aqA1, y, 0, 0, 0);
                sA[ct] = y;
            }
        }

        short* pw = Pw[wid];

        // ---- softmax numerator B -> P LDS (contiguous b64 writes) ----
        {
            const bool diag = (tile == nb - 1);
            #pragma unroll
            for (int ct = 0; ct < 4; ++ct) {
                float e[4];
                #pragma unroll
                for (int r = 0; r < 4; ++r) {
                    float x = sB[ct][r] * SC_LOG2E;
                    if (diag && (ct * 16 + quad * 4 + r > row_q)) x = -__builtin_inff();
                    e[r] = __builtin_amdgcn_exp2f(x);
                    lpB += e[r];
                }
                *(uint2*)(pw + prow + (((ct * 2 + (quad >> 1)) ^ l7) * 8) + (quad & 1) * 4)
                    = make_uint2(pk2(e[0], e[1]), pk2(e[2], e[3]));
            }
        }
        const bf16x8 pB0 = *(const bf16x8*)(pw + prow + fko0);
        const bf16x8 pB1 = *(const bf16x8*)(pw + prow + fko1);

        // ---- softmax numerator A (reuses Pw; wave-private, DS in-order) ----
        bf16x8 pA0, pA1;
        if (doA) {
            const bool diag = (tile == na - 1);
            #pragma unroll
            for (int ct = 0; ct < 4; ++ct) {
                float e[4];
                #pragma unroll
                for (int r = 0; r < 4; ++r) {
                    float x = sA[ct][r] * SC_LOG2E;
                    if (diag && (ct * 16 + quad * 4 + r > row_q)) x = -__builtin_inff();
                    e[r] = __builtin_amdgcn_exp2f(x);
                    lpA += e[r];
                }
                *(uint2*)(pw + prow + (((ct * 2 + (quad >> 1)) ^ l7) * 8) + (quad & 1) * 4)
                    = make_uint2(pk2(e[0], e[1]), pk2(e[2], e[3]));
            }
            pA0 = *(const bf16x8*)(pw + prow + fko0);
            pA1 = *(const bf16x8*)(pw + prow + fko1);
        }

        // ---- O^T += V^T·P^T : A = V-frag, B = P-frag ----
        #pragma unroll
        for (int nt = 0; nt < 4; ++nt) {
            const int rb = (nt * 16 + lcol) * 64;
            const bf16x8 v0 = *(const bf16x8*)(Vb + rb + fko0);
            const bf16x8 v1 = *(const bf16x8*)(Vb + rb + fko1);
            oB[nt] = __builtin_amdgcn_mfma_f32_16x16x32_bf16(v0, pB0, oB[nt], 0, 0, 0);
            oB[nt] = __builtin_amdgcn_mfma_f32_16x16x32_bf16(v1, pB1, oB[nt], 0, 0, 0);
            if (doA) {
                oA[nt] = __builtin_amdgcn_mfma_f32_16x16x32_bf16(v0, pA0, oA[nt], 0, 0, 0);
                oA[nt] = __builtin_amdgcn_mfma_f32_16x16x32_bf16(v1, pA1, oA[nt], 0, 0, 0);
            }
        }

        // ---- stage next tile into other buffer; prefetch tile+2 ----
        if (tile + 1 < nb) {
            STAGE(cur ^ 1);
            if (tile + 2 < nb) PREFETCH(tile + 2);
        }
        __syncthreads();
    }

    // ---- reduce softmax denom across quads (q = lcol) ----
    lpA += __shfl_xor(lpA, 16, 64); lpA += __shfl_xor(lpA, 32, 64);
    lpB += __shfl_xor(lpB, 16, 64); lpB += __shfl_xor(lpB, 32, 64);
    const float invA = 1.0f / lpA;
    const float invB = 1.0f / lpB;

    // ---- epilogue: O^T -> LDS transpose (reuse K/V buffers) -> coalesced store
    float* oa = (float*)Kl + wid * 1024;   // 16 q-rows x 64 d (swizzled chunks)
    float* ob = (float*)Vt + wid * 1024;
    #pragma unroll
    for (int nt = 0; nt < 4; ++nt) {
        const int off = lcol * 64 + (((nt * 4 + quad) ^ lcol) * 4);
        *(f32x4*)(oa + off) = oA[nt] * invA;
        *(f32x4*)(ob + off) = oB[nt] * invB;
    }
    const int qr = lane >> 2;
    const int cl = lane & 3;
    float* opA = Oh + (size_t)(q0a + wid * 16 + qr) * D_DIM;
    float* opB = Oh + (size_t)(q0b + wid * 16 + qr) * D_DIM;
    #pragma unroll
    for (int c = 0; c < 4; ++c) {
        const int off = qr * 64 + (((cl * 4 + c) ^ qr) * 4);
        *(float4*)(opA + cl * 16 + c * 4) = *(const float4*)(oa + off);
        *(float4*)(opB + cl * 16 + c * 4) = *(const float4*)(ob + off);
    }
}

extern "C" void kernel_launch(void* const* d_in, const int* in_sizes, int n_in,
                              void* d_out, int out_size, void* d_ws, size_t ws_size,
                              hipStream_t stream) {
    const float* Q = (const float*)d_in[0];
    const float* K = (const float*)d_in[1];
    const float* V = (const float*)d_in[2];
    float*       O = (float*)d_out;
    dim3 grid(S_LEN / BM / 2, 4 * 16);   // 16 complementary q-pairs x 64 heads
    fattn_kernel<<<grid, 256, 0, stream>>>(Q, K, V, O);
}